// Round 10
// baseline (931.884 us; speedup 1.0000x reference)
//
#include <hip/hip_runtime.h>
#include <math.h>

#define S    256
#define Hp   288
#define C    32
#define KY   12
#define NK   24
#define Bn   8
#define PI_D 3.14159265358979323846264338327950288

// workspace offsets (in floats)
#define SZ_TW  (NK*Hp*2)                // 13824  [k][x] layout, k<24
#define OFF_TW 0
#define OFF_TWT (OFF_TW + SZ_TW)
#define SZ_TWT (Hp*KY*2)                // 6912   [y][k][2] transposed, k<12
#define OFF_H  (OFF_TWT + SZ_TWT)
#define SZ_H   (Bn*C*Hp*Hp)             // 21233664
#define OFF_Y  (OFF_H + SZ_H)
#define SZ_Y   (Bn*C*Hp*KY*2)           // 1769472
#define OFF_X  (OFF_Y + SZ_Y)
#define SZ_X   (Bn*C*NK*KY*2)           // 147456 (one half-partial)
#define OFF_O  (OFF_X + 2*SZ_X)
#define SZ_O   SZ_X
#define OFF_Z  (OFF_O + SZ_O)
#define SZ_Z   (Bn*Hp*C*KY*2)           // 1769472
#define OFF_T  (OFF_Z + SZ_Z)
#define SZ_T   (Bn*S*S*2)               // 1048576

#define GELU(v) (0.5f*(v)*(1.0f+erff((v)*0.70710678118654752f)))
#define SCHED_FENCE() __builtin_amdgcn_sched_barrier(0)

// twiddle tables: tw[k][x] (k<24, both signs) and transposed twT[x][k][2] (k<12)
__global__ void k_tw(float* __restrict__ tw, float* __restrict__ twT) {
    int i = blockIdx.x * 256 + threadIdx.x;
    if (i >= NK * Hp) return;
    int k = i / Hp, xx = i % Hp;
    int f = (k < KY) ? k : (k + 264);
    int m = (f * xx) % Hp;                        // exact integer phase reduction
    double th = (2.0 * PI_D * (double)m) / (double)Hp;
    float c = (float)cos(th), s = (float)sin(th);
    tw[2 * i] = c; tw[2 * i + 1] = s;
    if (k < KY) { twT[xx * 24 + 2 * k] = c; twT[xx * 24 + 2 * k + 1] = s; }
}

// rotate tc by one y-step: tc[k] *= e^{2*pi*i*k/288} (k=1..11; k=0 is (1,0))
__device__ __forceinline__ void rot_tc(float* tc, const float* rk) {
    #pragma unroll
    for (int k = 1; k < 12; ++k) {
        float c0 = tc[2*k], s0 = tc[2*k+1];
        tc[2*k]   = c0 * rk[2*k]   - s0 * rk[2*k+1];
        tc[2*k+1] = c0 * rk[2*k+1] + s0 * rk[2*k];
    }
}

// gather + grid + fc0 + pad -> h row, fused forward DFT-y -> Y (r7 version).
__global__ __launch_bounds__(256, 1) void k_embed(
        const float* __restrict__ xin, const int* __restrict__ d2v,
        const float* __restrict__ fw, const float* __restrict__ fb,
        const float* __restrict__ twT, float* __restrict__ h, float* __restrict__ Y) {
    __shared__ __align__(16) float xs[256];
    __shared__ __align__(16) float YP[3072];
    int x = blockIdx.x, b = blockIdx.y, tid = threadIdx.x;
    size_t rowbase = (size_t)b * 2654208 + (size_t)x * 288;
    if (x >= S) {                                   // pad rows: h=0, Y=0
        for (int i = tid; i < 32 * 72; i += 256) {
            int c = i / 72, q = i % 72;
            *(float4*)&h[rowbase + (size_t)c * 82944 + q * 4] = make_float4(0, 0, 0, 0);
        }
        for (int i = tid; i < 768; i += 256)
            Y[((size_t)(b * 32 + i / 24) * 288 + x) * 24 + (i % 24)] = 0.f;
        return;
    }
    xs[tid] = xin[b * 65536 + d2v[x * 256 + tid]];
    int o = tid & 31, g = tid >> 5;
    float w0 = fw[o * 3], w1 = fw[o * 3 + 1], w2 = fw[o * 3 + 2], bb = fb[o];
    float gx = x * (1.0f / 255.0f);
    float rk[24];
    #pragma unroll
    for (int q = 0; q < 6; ++q) *(float4*)&rk[4 * q] = *(const float4*)&twT[24 + 4 * q];
    __syncthreads();
    float pr[12], pi[12];
    #pragma unroll
    for (int k = 0; k < 12; ++k) { pr[k] = 0.f; pi[k] = 0.f; }
    #pragma unroll 1
    for (int c3 = 0; c3 < 3; ++c3) {
        int ybase = g * 36 + c3 * 12;
        float tc[24];
        {
            const float* tg = twT + ybase * 24;
            #pragma unroll
            for (int q = 0; q < 6; ++q) *(float4*)&tc[4 * q] = *(const float4*)&tg[4 * q];
        }
        float acc[12];
        #pragma unroll
        for (int j = 0; j < 12; ++j) {
            int y = ybase + j;
            acc[j] = (y < S) ? (w0 * xs[y < S ? y : 0] + w1 * gx + w2 * (y * (1.0f / 255.0f)) + bb) : 0.f;
        }
        float* hw = h + rowbase + (size_t)o * 82944 + ybase;
        #pragma unroll
        for (int q = 0; q < 3; ++q)
            *(float4*)&hw[4 * q] = make_float4(acc[4*q], acc[4*q+1], acc[4*q+2], acc[4*q+3]);
        SCHED_FENCE();
        #pragma unroll
        for (int j = 0; j < 12; ++j) {
            float v = acc[j];
            pr[0] += v;                              // k=0: tc = (1,0) always
            #pragma unroll
            for (int k = 1; k < 12; ++k) { pr[k] += v * tc[2 * k]; pi[k] -= v * tc[2 * k + 1]; }
            if (j < 11) rot_tc(tc, rk);
        }
        SCHED_FENCE();
    }
    #pragma unroll
    for (int k = 0; k < 12; ++k) { pr[k] += __shfl_xor(pr[k], 32); pi[k] += __shfl_xor(pi[k], 32); }
    if ((tid & 32) == 0) {
        float* dst = YP + ((tid >> 6) * 32 + o) * 24;
        #pragma unroll
        for (int k = 0; k < 12; ++k) { dst[2 * k] = pr[k]; dst[2 * k + 1] = pi[k]; }
    }
    __syncthreads();
    for (int i = tid; i < 768; i += 256) {
        float s = YP[i] + YP[768 + i] + YP[1536 + i] + YP[2304 + i];
        Y[((size_t)(b * 32 + i / 24) * 288 + x) * 24 + (i % 24)] = s;
    }
}

// forward DFT along x, split into 2 x-half partials. X[half][b][c][k][ky]
__global__ __launch_bounds__(288) void k_dftx(const float* __restrict__ Y,
                                              const float* __restrict__ tw,
                                              float* __restrict__ X) {
    __shared__ __align__(16) float Ys[144 * 24];
    int c = blockIdx.x, b = blockIdx.y, half = blockIdx.z, tid = threadIdx.x;
    const float* Yb = Y + (size_t)(b * 32 + c) * 6912 + half * 3456;
    for (int i = tid; i < 864; i += 288)
        *(float4*)&Ys[4 * i] = *(const float4*)&Yb[4 * i];
    __syncthreads();
    int k = tid / 12, ky = tid % 12;
    const float* twk = tw + k * 576 + half * 288;
    float xr = 0.f, xi = 0.f;
    #pragma unroll 4
    for (int xx = 0; xx < 144; ++xx) {
        float yr = Ys[xx * 24 + 2 * ky], yi = Ys[xx * 24 + 2 * ky + 1];
        float cc = twk[2 * xx], ss = twk[2 * xx + 1];
        xr += yr * cc + yi * ss;      // e^{-i t}
        xi += yi * cc - yr * ss;
    }
    size_t oo = (size_t)half * SZ_X + ((size_t)(b * 32 + c) * 288 + tid) * 2;
    X[oo] = xr; X[oo + 1] = xi;
}

// complex channel mix: O = sum_i (Xh0+Xh1) * W_l
__global__ void k_spec(const float* __restrict__ X,
                       const float* __restrict__ w1r, const float* __restrict__ w1i,
                       const float* __restrict__ w2r, const float* __restrict__ w2i,
                       float* __restrict__ O, int l) {
    int t = blockIdx.x * 256 + threadIdx.x;
    int ky = t % KY; int k = (t / KY) % NK; int o = (t / (NK * KY)) % C; int b = t / (C * NK * KY);
    int kk = (k < KY) ? k : (k - KY);
    const float* wr = (k < KY) ? w1r : w2r;
    const float* wi = (k < KY) ? w1i : w2i;
    size_t wbase = (size_t)l * C * C * 144 + (size_t)o * 144 + kk * 12 + ky;
    size_t xbase = (size_t)b * C * NK * KY * 2 + (k * KY + ky) * 2;
    float ar = 0.f, ai = 0.f;
    #pragma unroll 8
    for (int i = 0; i < C; ++i) {
        size_t xo = xbase + (size_t)i * NK * KY * 2;
        float xr = X[xo]     + X[SZ_X + xo];
        float xi = X[xo + 1] + X[SZ_X + xo + 1];
        float wrr = wr[wbase + (size_t)i * C * 144];
        float wii = wi[wbase + (size_t)i * C * 144];
        ar += xr * wrr - xi * wii;
        ai += xr * wii + xi * wrr;
    }
    size_t oo = (((size_t)b * C + o) * NK * KY + k * KY + ky) * 2;
    O[oo] = ar; O[oo + 1] = ai;
}

// inverse DFT along x: Z[b][x][c][ky]
__global__ __launch_bounds__(384) void k_idftx(const float* __restrict__ O,
                                               const float* __restrict__ tw,
                                               float* __restrict__ Z) {
    int x0 = blockIdx.x * 32; int c = blockIdx.y, b = blockIdx.z;
    int row = threadIdx.x & 31, ky = threadIdx.x >> 5;
    int x = x0 + row;
    const float* Ob = O + ((size_t)(b * C + c)) * NK * KY * 2 + ky * 2;
    float zr = 0.f, zi = 0.f;
    #pragma unroll
    for (int k = 0; k < NK; ++k) {
        float orr = Ob[k * KY * 2], oii = Ob[k * KY * 2 + 1];
        float cc = tw[(k * Hp + x) * 2], ss = tw[(k * Hp + x) * 2 + 1];
        zr += orr * cc - oii * ss;        // e^{+i t}
        zi += orr * ss + oii * cc;
    }
    size_t o = ((((size_t)b * Hp + x) * C + c) * KY + ky) * 2;
    Z[o] = zr; Z[o + 1] = zi;
}

// pair epilogue: 12 pairs (ylo, ylo+144). tw[k][ylo] = twq[k][rowq]*i^{k*QP},
// tw[k][ylo+144] = (-1)^k tw[k][ylo]. One twiddle read + one A_k product set
// serves BOTH y's (even/odd partial-sum split); fDFT uses u=vl+vh / v=vl-vh.
template<int QP>
__device__ __forceinline__ void epi_pairs(const float* __restrict__ twq, int rowq,
                                          float* al, float* ah,
                                          const float* zr, const float* zi,
                                          float* pr, float* pi, int gelu_f, int wy) {
    #pragma unroll
    for (int j = 0; j < 12; ++j) {
        const float* tg = twq + (rowq + j) * 24;
        float tc[24];
        #pragma unroll
        for (int q = 0; q < 6; ++q) *(float4*)&tc[4 * q] = *(const float4*)&tg[4 * q];
        float SAE = 0.f, SAO = 0.f;
        #pragma unroll
        for (int k = 1; k < 12; ++k) {
            const int e = (k * QP) & 3;
            float c = tc[2 * k], s = tc[2 * k + 1];
            float A;
            if      (e == 0) A =  zr[k] * c - zi[k] * s;
            else if (e == 1) A = -zr[k] * s - zi[k] * c;
            else if (e == 2) A = -zr[k] * c + zi[k] * s;
            else             A =  zr[k] * s + zi[k] * c;
            if (k & 1) SAO += A; else SAE += A;
        }
        float spl = zr[0] + 2.f * (SAE + SAO);
        float sph = zr[0] + 2.f * (SAE - SAO);
        float vl = al[j] + spl * (1.0f / 82944.0f);
        float vh = ah[j] + sph * (1.0f / 82944.0f);
        if (gelu_f) { vl = GELU(vl); vh = GELU(vh); }
        al[j] = vl; ah[j] = vh;
        if (wy) {
            float u = vl + vh, v = vl - vh;
            pr[0] += u;
            #pragma unroll
            for (int k = 1; k < 12; ++k) {
                const int e = (k * QP) & 3;
                float c = tc[2 * k], s = tc[2 * k + 1];
                float w_ = (k & 1) ? v : u;
                if      (e == 0) { pr[k] += w_ * c; pi[k] -= w_ * s; }
                else if (e == 1) { pr[k] -= w_ * s; pi[k] -= w_ * c; }
                else if (e == 2) { pr[k] -= w_ * c; pi[k] += w_ * s; }
                else             { pr[k] += w_ * s; pi[k] += w_ * c; }
            }
        }
        SCHED_FENCE();
    }
}

// fused: 1x1 conv + inverse DFT-y + bias + gelu (in place) + forward DFT-y -> Y.
// 384 threads = 12 y-groups x 32 o-lanes; group g owns pairs (12g+j, 12g+144+j)
// so conv reads stay aligned b128 while the epilogue shares twiddles/products
// across the +-144 pair. QP = (g>=6) wave-uniform quarter-table template.
// LDS: hs 36.9 KB (aliased as YP) + twq 6.9 KB + cws 4.2 KB = 48 KB, 3 blk/CU
// = 18 waves/CU.
__global__ __launch_bounds__(384, 1) void k_conv(
        float* __restrict__ h, const float* __restrict__ Z,
        const float* __restrict__ cw, const float* __restrict__ cb,
        const float* __restrict__ twT, float* __restrict__ Y,
        int l, int flags) {
    __shared__ __align__(16) float hs[9216];        // aliased as YP at the end
    __shared__ __align__(16) float twq[1728];       // quarter table, rows y<72
    __shared__ __align__(16) float cws[32 * 33];
    int x = blockIdx.x, b = blockIdx.y, tid = threadIdx.x;
    int o = tid & 31, g = tid >> 5;                  // g in [0,12)
    size_t rowbase = (size_t)b * 2654208 + (size_t)x * 288;
    const float* hb = h + rowbase;
    for (int i = tid; i < 432; i += 384)
        *(float4*)&twq[4 * i] = *(const float4*)&twT[4 * i];
    for (int i = tid; i < 1024; i += 384)
        cws[(i >> 5) * 33 + (i & 31)] = cw[l * 1024 + i];
    for (int i = tid; i < 2304; i += 384)
        *(float4*)&hs[4 * i] = *(const float4*)&hb[(size_t)(i / 72) * 82944 + (i % 72) * 4];
    // spectral modes for channel o (VGPRs, loaded once; coalesced over o)
    const float* Zr = Z + ((size_t)(b * 288 + x) * 32 + o) * 24;
    float zr[12], zi[12];
    #pragma unroll
    for (int q = 0; q < 6; ++q) {
        float4 zv = *(const float4*)&Zr[4 * q];
        zr[2*q] = zv.x; zi[2*q] = zv.y; zr[2*q+1] = zv.z; zi[2*q+1] = zv.w;
    }
    float bias = cb[l * 32 + o];
    float pr[12], pi[12];
    #pragma unroll
    for (int k = 0; k < 12; ++k) { pr[k] = 0.f; pi[k] = 0.f; }
    const int gelu_f = flags & 1, wy = flags & 2;
    __syncthreads();
    const int yb = g * 12;                           // 16B-aligned
    float al[12], ah[12];
    #pragma unroll
    for (int j = 0; j < 12; ++j) { al[j] = bias; ah[j] = bias; }
    #pragma unroll 8
    for (int c = 0; c < 32; ++c) {
        float w = cws[o * 33 + c];
        const float* hr = &hs[c * 288 + yb];
        float4 l0 = *(const float4*)&hr[0];
        float4 l1 = *(const float4*)&hr[4];
        float4 l2 = *(const float4*)&hr[8];
        float4 h0 = *(const float4*)&hr[144];
        float4 h1 = *(const float4*)&hr[148];
        float4 h2 = *(const float4*)&hr[152];
        al[0] += l0.x * w; al[1] += l0.y * w; al[2]  += l0.z * w; al[3]  += l0.w * w;
        al[4] += l1.x * w; al[5] += l1.y * w; al[6]  += l1.z * w; al[7]  += l1.w * w;
        al[8] += l2.x * w; al[9] += l2.y * w; al[10] += l2.z * w; al[11] += l2.w * w;
        ah[0] += h0.x * w; ah[1] += h0.y * w; ah[2]  += h0.z * w; ah[3]  += h0.w * w;
        ah[4] += h1.x * w; ah[5] += h1.y * w; ah[6]  += h1.z * w; ah[7]  += h1.w * w;
        ah[8] += h2.x * w; ah[9] += h2.y * w; ah[10] += h2.z * w; ah[11] += h2.w * w;
    }
    SCHED_FENCE();
    if (g < 6) epi_pairs<0>(twq, yb,      al, ah, zr, zi, pr, pi, gelu_f, wy);
    else       epi_pairs<1>(twq, yb - 72, al, ah, zr, zi, pr, pi, gelu_f, wy);
    float* hw = h + rowbase + (size_t)o * 82944 + yb;
    #pragma unroll
    for (int q = 0; q < 3; ++q) {
        *(float4*)&hw[4 * q]       = make_float4(al[4*q], al[4*q+1], al[4*q+2], al[4*q+3]);
        *(float4*)&hw[144 + 4 * q] = make_float4(ah[4*q], ah[4*q+1], ah[4*q+2], ah[4*q+3]);
    }
    if (wy) {
        #pragma unroll
        for (int k = 0; k < 12; ++k) { pr[k] += __shfl_xor(pr[k], 32); pi[k] += __shfl_xor(pi[k], 32); }
        __syncthreads();                             // all hs conv reads done
        float* YP = hs;                              // 6 wave-partials x 768
        if ((tid & 32) == 0) {
            float* dst = YP + ((tid >> 6) * 32 + o) * 24;
            #pragma unroll
            for (int k = 0; k < 12; ++k) { dst[2 * k] = pr[k]; dst[2 * k + 1] = pi[k]; }
        }
        __syncthreads();
        for (int i = tid; i < 768; i += 384) {
            float s = YP[i] + YP[768 + i] + YP[1536 + i] + YP[2304 + i]
                    + YP[3072 + i] + YP[3840 + i];
            Y[((size_t)(b * 32 + i / 24) * 288 + x) * 24 + (i % 24)] = s;
        }
    }
}

// per-pixel MLP 32 -> gelu(128) -> 2, crop, 2 pixels/thread
__global__ __launch_bounds__(256) void k_mlp(const float* __restrict__ h,
                                             const float* __restrict__ w1, const float* __restrict__ b1,
                                             const float* __restrict__ w2, const float* __restrict__ b2,
                                             float* __restrict__ tmp) {
    int bid = blockIdx.x;                          // 1024 blocks
    int b = bid >> 7;
    int x = ((bid & 127) << 1) + (threadIdx.x >> 7);
    int lane = threadIdx.x & 127;
    const float* hb = h + (size_t)b * 2654208 + (size_t)x * 288;
    float hc0[32], hc1[32];
    #pragma unroll
    for (int c = 0; c < 32; ++c) {
        hc0[c] = hb[(size_t)c * 82944 + lane];
        hc1[c] = hb[(size_t)c * 82944 + lane + 128];
    }
    float o00 = 0.f, o01 = 0.f, o10 = 0.f, o11 = 0.f;
    for (int f = 0; f < 128; ++f) {
        float a0 = b1[f], a1 = a0;
        #pragma unroll
        for (int c = 0; c < 32; ++c) {
            float w = w1[f * 32 + c];
            a0 += hc0[c] * w; a1 += hc1[c] * w;
        }
        float wa = w2[f], wb = w2[128 + f];
        float g0 = GELU(a0), g1 = GELU(a1);
        o00 += g0 * wa; o01 += g0 * wb;
        o10 += g1 * wa; o11 += g1 * wb;
    }
    float bb0 = b2[0], bb1 = b2[1];
    int p0 = x * 256 + lane;
    size_t base = (size_t)b * 65536;
    *(float2*)&tmp[(base + p0) * 2]       = make_float2(o00 + bb0, o01 + bb1);
    *(float2*)&tmp[(base + p0 + 128) * 2] = make_float2(o10 + bb0, o11 + bb1);
}

// out[b][j][d] = tmp[b][v2d[j]][d]
__global__ void k_scatter(const float* __restrict__ tmp, const int* __restrict__ v2d,
                          float* __restrict__ out) {
    int id = blockIdx.x * 256 + threadIdx.x;
    int b = id >> 16; int j = id & 65535;
    int p = v2d[j];
    const float2 v = *(const float2*)(tmp + ((size_t)(b << 16) + p) * 2);
    *(float2*)(out + (size_t)id * 2) = v;
}

extern "C" void kernel_launch(void* const* d_in, const int* in_sizes, int n_in,
                              void* d_out, int out_size, void* d_ws, size_t ws_size,
                              hipStream_t stream) {
    const float* xin   = (const float*)d_in[0];
    const int*   d2v   = (const int*)  d_in[1];
    const int*   v2d   = (const int*)  d_in[2];
    const float* fc0w  = (const float*)d_in[3];
    const float* fc0b  = (const float*)d_in[4];
    const float* w1r   = (const float*)d_in[5];
    const float* w1i   = (const float*)d_in[6];
    const float* w2r   = (const float*)d_in[7];
    const float* w2i   = (const float*)d_in[8];
    const float* cw    = (const float*)d_in[9];
    const float* cb    = (const float*)d_in[10];
    const float* mw1   = (const float*)d_in[11];
    const float* mb1   = (const float*)d_in[12];
    const float* mw2   = (const float*)d_in[13];
    const float* mb2   = (const float*)d_in[14];

    float* ws  = (float*)d_ws;
    float* TW  = ws + OFF_TW;
    float* TWT = ws + OFF_TWT;
    float* H   = ws + OFF_H;
    float* Y   = ws + OFF_Y;
    float* X   = ws + OFF_X;
    float* O   = ws + OFF_O;
    float* Z   = ws + OFF_Z;
    float* T   = ws + OFF_T;

    k_tw<<<(NK * Hp + 255) / 256, 256, 0, stream>>>(TW, TWT);
    k_embed<<<dim3(Hp, Bn), 256, 0, stream>>>(xin, d2v, fc0w, fc0b, TWT, H, Y);

    for (int l = 0; l < 4; ++l) {
        k_dftx<<<dim3(32, Bn, 2), 288, 0, stream>>>(Y, TW, X);
        k_spec<<<(Bn * C * NK * KY) / 256, 256, 0, stream>>>(X, w1r, w1i, w2r, w2i, O, l);
        k_idftx<<<dim3(9, 32, Bn), 384, 0, stream>>>(O, TW, Z);
        k_conv<<<dim3(Hp, Bn), 384, 0, stream>>>(H, Z, cw, cb, TWT, Y, l, (l != 3) ? 3 : 0);
    }

    k_mlp<<<1024, 256, 0, stream>>>(H, mw1, mb1, mw2, mb2, T);
    k_scatter<<<(Bn * S * S) / 256, 256, 0, stream>>>(T, v2d, (float*)d_out);
}

// Round 11
// 820.265 us; speedup vs baseline: 1.1361x; 1.1361x over previous
//
#include <hip/hip_runtime.h>
#include <math.h>

#define S    256
#define Hp   288
#define C    32
#define KY   12
#define NK   24
#define Bn   8
#define PI_D 3.14159265358979323846264338327950288

// workspace offsets (in floats)
#define SZ_TW  (NK*Hp*2)                // 13824  [k][x] layout, k<24
#define OFF_TW 0
#define OFF_TWT (OFF_TW + SZ_TW)
#define SZ_TWT (Hp*KY*2)                // 6912   [y][k][2] transposed, k<12
#define OFF_H  (OFF_TWT + SZ_TWT)
#define SZ_H   (Bn*C*Hp*Hp)             // 21233664
#define OFF_Y  (OFF_H + SZ_H)
#define SZ_Y   (Bn*C*Hp*KY*2)           // 1769472
#define OFF_X  (OFF_Y + SZ_Y)
#define SZ_X   (Bn*C*NK*KY*2)           // 147456 (one half-partial)
#define OFF_O  (OFF_X + 2*SZ_X)
#define SZ_O   SZ_X
#define OFF_Z  (OFF_O + SZ_O)
#define SZ_Z   (Bn*Hp*C*KY*2)           // 1769472
#define OFF_T  (OFF_Z + SZ_Z)
#define SZ_T   (Bn*S*S*2)               // 1048576

#define GELU(v) (0.5f*(v)*(1.0f+erff((v)*0.70710678118654752f)))
#define SCHED_FENCE() __builtin_amdgcn_sched_barrier(0)

// twiddle tables: tw[k][x] (k<24, both signs) and transposed twT[x][k][2] (k<12)
__global__ void k_tw(float* __restrict__ tw, float* __restrict__ twT) {
    int i = blockIdx.x * 256 + threadIdx.x;
    if (i >= NK * Hp) return;
    int k = i / Hp, xx = i % Hp;
    int f = (k < KY) ? k : (k + 264);
    int m = (f * xx) % Hp;                        // exact integer phase reduction
    double th = (2.0 * PI_D * (double)m) / (double)Hp;
    float c = (float)cos(th), s = (float)sin(th);
    tw[2 * i] = c; tw[2 * i + 1] = s;
    if (k < KY) { twT[xx * 24 + 2 * k] = c; twT[xx * 24 + 2 * k + 1] = s; }
}

// embed main body, templated on quarter Q (wave-uniform: Q = tid>>6).
// tw[k][yq+72Q] = twq[k][yq] * i^{kQ}; forward-DFT conj gives i^{-kQ}
// operand-swap/sign patterns (verified in r9's epi12 run).
template<int Q>
__device__ __forceinline__ void embed_body(
        const float* __restrict__ xs, const float* __restrict__ twq,
        float* __restrict__ h, size_t rowbase, int o, int g,
        float w0, float w1, float w2, float bb, float gx,
        float* pr, float* pi) {
    #pragma unroll 1
    for (int c3 = 0; c3 < 3; ++c3) {
        int ybase = g * 36 + c3 * 12;
        int rowq  = (g & 1) * 36 + c3 * 12;
        float acc[12];
        #pragma unroll
        for (int j = 0; j < 12; ++j) {
            int y = ybase + j;
            acc[j] = (y < S) ? (w0 * xs[y < S ? y : 0] + w1 * gx + w2 * (y * (1.0f / 255.0f)) + bb) : 0.f;
        }
        float* hw = h + rowbase + (size_t)o * 82944 + ybase;
        #pragma unroll
        for (int q = 0; q < 3; ++q)
            *(float4*)&hw[4 * q] = make_float4(acc[4*q], acc[4*q+1], acc[4*q+2], acc[4*q+3]);
        SCHED_FENCE();
        #pragma unroll
        for (int jp = 0; jp < 6; ++jp) {
            #pragma unroll
            for (int u = 0; u < 2; ++u) {
                int j = jp * 2 + u;
                const float* tg = twq + (rowq + j) * 24;
                float tc[24];
                #pragma unroll
                for (int q = 0; q < 6; ++q) *(float4*)&tc[4 * q] = *(const float4*)&tg[4 * q];
                float v = acc[j];
                pr[0] += v;                          // k=0: (1,0) in all quarters
                #pragma unroll
                for (int k = 1; k < 12; ++k) {
                    const int e = (k * Q) & 3;
                    float c = tc[2 * k], s = tc[2 * k + 1];
                    if      (e == 0) { pr[k] += v * c; pi[k] -= v * s; }
                    else if (e == 1) { pr[k] -= v * s; pi[k] -= v * c; }
                    else if (e == 2) { pr[k] -= v * c; pi[k] += v * s; }
                    else             { pr[k] += v * s; pi[k] += v * c; }
                }
            }
            SCHED_FENCE();
        }
    }
}

// gather + grid + fc0 + pad -> h row, fused forward DFT-y -> Y.
// Quarter twiddle table in LDS (6.9 KB) + wave-uniform Q templates: low VALU
// (no rotation chains), low LDS (20 KB total) -> high occupancy.
__global__ __launch_bounds__(256, 1) void k_embed(
        const float* __restrict__ xin, const int* __restrict__ d2v,
        const float* __restrict__ fw, const float* __restrict__ fb,
        const float* __restrict__ twT, float* __restrict__ h, float* __restrict__ Y) {
    __shared__ __align__(16) float xs[256];
    __shared__ __align__(16) float twq[1728];       // quarter table, rows y<72
    __shared__ __align__(16) float YP[3072];
    int x = blockIdx.x, b = blockIdx.y, tid = threadIdx.x;
    size_t rowbase = (size_t)b * 2654208 + (size_t)x * 288;
    if (x >= S) {                                   // pad rows: h=0, Y=0
        for (int i = tid; i < 32 * 72; i += 256) {
            int c = i / 72, q = i % 72;
            *(float4*)&h[rowbase + (size_t)c * 82944 + q * 4] = make_float4(0, 0, 0, 0);
        }
        for (int i = tid; i < 768; i += 256)
            Y[((size_t)(b * 32 + i / 24) * 288 + x) * 24 + (i % 24)] = 0.f;
        return;
    }
    for (int i = tid; i < 432; i += 256)
        *(float4*)&twq[4 * i] = *(const float4*)&twT[4 * i];
    xs[tid] = xin[b * 65536 + d2v[x * 256 + tid]];
    int o = tid & 31, g = tid >> 5;
    float w0 = fw[o * 3], w1 = fw[o * 3 + 1], w2 = fw[o * 3 + 2], bb = fb[o];
    float gx = x * (1.0f / 255.0f);
    __syncthreads();
    float pr[12], pi[12];
    #pragma unroll
    for (int k = 0; k < 12; ++k) { pr[k] = 0.f; pi[k] = 0.f; }
    switch (tid >> 6) {                              // quarter = wave id (uniform)
        case 0: embed_body<0>(xs, twq, h, rowbase, o, g, w0, w1, w2, bb, gx, pr, pi); break;
        case 1: embed_body<1>(xs, twq, h, rowbase, o, g, w0, w1, w2, bb, gx, pr, pi); break;
        case 2: embed_body<2>(xs, twq, h, rowbase, o, g, w0, w1, w2, bb, gx, pr, pi); break;
        default: embed_body<3>(xs, twq, h, rowbase, o, g, w0, w1, w2, bb, gx, pr, pi); break;
    }
    #pragma unroll
    for (int k = 0; k < 12; ++k) { pr[k] += __shfl_xor(pr[k], 32); pi[k] += __shfl_xor(pi[k], 32); }
    if ((tid & 32) == 0) {
        float* dst = YP + ((tid >> 6) * 32 + o) * 24;
        #pragma unroll
        for (int k = 0; k < 12; ++k) { dst[2 * k] = pr[k]; dst[2 * k + 1] = pi[k]; }
    }
    __syncthreads();
    for (int i = tid; i < 768; i += 256) {
        float s = YP[i] + YP[768 + i] + YP[1536 + i] + YP[2304 + i];
        Y[((size_t)(b * 32 + i / 24) * 288 + x) * 24 + (i % 24)] = s;
    }
}

// forward DFT along x, split into 2 x-half partials. X[half][b][c][k][ky]
__global__ __launch_bounds__(288) void k_dftx(const float* __restrict__ Y,
                                              const float* __restrict__ tw,
                                              float* __restrict__ X) {
    __shared__ __align__(16) float Ys[144 * 24];
    int c = blockIdx.x, b = blockIdx.y, half = blockIdx.z, tid = threadIdx.x;
    const float* Yb = Y + (size_t)(b * 32 + c) * 6912 + half * 3456;
    for (int i = tid; i < 864; i += 288)
        *(float4*)&Ys[4 * i] = *(const float4*)&Yb[4 * i];
    __syncthreads();
    int k = tid / 12, ky = tid % 12;
    const float* twk = tw + k * 576 + half * 288;
    float xr = 0.f, xi = 0.f;
    #pragma unroll 4
    for (int xx = 0; xx < 144; ++xx) {
        float yr = Ys[xx * 24 + 2 * ky], yi = Ys[xx * 24 + 2 * ky + 1];
        float cc = twk[2 * xx], ss = twk[2 * xx + 1];
        xr += yr * cc + yi * ss;      // e^{-i t}
        xi += yi * cc - yr * ss;
    }
    size_t oo = (size_t)half * SZ_X + ((size_t)(b * 32 + c) * 288 + tid) * 2;
    X[oo] = xr; X[oo + 1] = xi;
}

// complex channel mix: O = sum_i (Xh0+Xh1) * W_l
__global__ void k_spec(const float* __restrict__ X,
                       const float* __restrict__ w1r, const float* __restrict__ w1i,
                       const float* __restrict__ w2r, const float* __restrict__ w2i,
                       float* __restrict__ O, int l) {
    int t = blockIdx.x * 256 + threadIdx.x;
    int ky = t % KY; int k = (t / KY) % NK; int o = (t / (NK * KY)) % C; int b = t / (C * NK * KY);
    int kk = (k < KY) ? k : (k - KY);
    const float* wr = (k < KY) ? w1r : w2r;
    const float* wi = (k < KY) ? w1i : w2i;
    size_t wbase = (size_t)l * C * C * 144 + (size_t)o * 144 + kk * 12 + ky;
    size_t xbase = (size_t)b * C * NK * KY * 2 + (k * KY + ky) * 2;
    float ar = 0.f, ai = 0.f;
    #pragma unroll 8
    for (int i = 0; i < C; ++i) {
        size_t xo = xbase + (size_t)i * NK * KY * 2;
        float xr = X[xo]     + X[SZ_X + xo];
        float xi = X[xo + 1] + X[SZ_X + xo + 1];
        float wrr = wr[wbase + (size_t)i * C * 144];
        float wii = wi[wbase + (size_t)i * C * 144];
        ar += xr * wrr - xi * wii;
        ai += xr * wii + xi * wrr;
    }
    size_t oo = (((size_t)b * C + o) * NK * KY + k * KY + ky) * 2;
    O[oo] = ar; O[oo + 1] = ai;
}

// inverse DFT along x: Z[b][x][c][ky]
__global__ __launch_bounds__(384) void k_idftx(const float* __restrict__ O,
                                               const float* __restrict__ tw,
                                               float* __restrict__ Z) {
    int x0 = blockIdx.x * 32; int c = blockIdx.y, b = blockIdx.z;
    int row = threadIdx.x & 31, ky = threadIdx.x >> 5;
    int x = x0 + row;
    const float* Ob = O + ((size_t)(b * C + c)) * NK * KY * 2 + ky * 2;
    float zr = 0.f, zi = 0.f;
    #pragma unroll
    for (int k = 0; k < NK; ++k) {
        float orr = Ob[k * KY * 2], oii = Ob[k * KY * 2 + 1];
        float cc = tw[(k * Hp + x) * 2], ss = tw[(k * Hp + x) * 2 + 1];
        zr += orr * cc - oii * ss;        // e^{+i t}
        zi += orr * ss + oii * cc;
    }
    size_t o = ((((size_t)b * Hp + x) * C + c) * KY + ky) * 2;
    Z[o] = zr; Z[o + 1] = zi;
}

// fused: 1x1 conv (weights in LDS) + inverse DFT-y + bias + gelu (in place)
// + forward DFT-y -> Y (flags bit1). This is the r4 kernel (best measured,
// 126 us) restored verbatim; only the twy staging changed: twy is byte-
// identical to twT, so stage with contiguous b128 (kills the 221k bank
// conflicts of the old strided float2 gather). LDS 69.6 KB, 2 blocks/CU.
__global__ __launch_bounds__(256, 1) void k_conv(
        float* __restrict__ h, const float* __restrict__ Z,
        const float* __restrict__ cw, const float* __restrict__ cb,
        const float* __restrict__ twT, float* __restrict__ Y,
        int l, int flags) {
    __shared__ __align__(16) float hs[32 * 292];
    __shared__ __align__(16) float twy[288 * 24];   // [y][k][2]; reused as YP
    __shared__ __align__(16) float cws[32 * 33];
    __shared__ float cbs[32];
    int x = blockIdx.x, b = blockIdx.y, tid = threadIdx.x;
    size_t rowbase = (size_t)b * 2654208 + (size_t)x * 288;
    const float* hb = h + rowbase;
    for (int i = tid; i < 32 * 72; i += 256) {
        int c = i / 72, q = i % 72;
        *(float4*)&hs[c * 292 + q * 4] = *(const float4*)&hb[(size_t)c * 82944 + q * 4];
    }
    for (int i = tid; i < 1728; i += 256)
        *(float4*)&twy[4 * i] = *(const float4*)&twT[4 * i];
    for (int i = tid; i < 32 * 32; i += 256)
        cws[(i >> 5) * 33 + (i & 31)] = cw[l * 1024 + i];
    if (tid < 32) cbs[tid] = cb[l * 32 + tid];
    int o = tid & 31, g = tid >> 5;
    // spectral modes for channel o (kept in VGPRs; loaded once)
    const float* Zr = Z + ((size_t)(b * 288 + x) * 32 + o) * 24;
    float zr[12], zi[12];
    #pragma unroll
    for (int q = 0; q < 6; ++q) {
        float4 zv = *(const float4*)&Zr[4 * q];
        zr[2*q] = zv.x; zi[2*q] = zv.y; zr[2*q+1] = zv.z; zi[2*q+1] = zv.w;
    }
    __syncthreads();
    float bias = cbs[o];
    float pr[12], pi[12];
    #pragma unroll
    for (int k = 0; k < 12; ++k) { pr[k] = 0.f; pi[k] = 0.f; }
    const int gelu_f = flags & 1, wy = flags & 2;
    #pragma unroll 1
    for (int c3 = 0; c3 < 3; ++c3) {
        int ybase = g * 36 + c3 * 12;
        float acc[12];
        #pragma unroll
        for (int j = 0; j < 12; ++j) acc[j] = bias;
        #pragma unroll 8
        for (int c = 0; c < 32; ++c) {
            float w = cws[o * 33 + c];
            const float* hr = &hs[c * 292 + ybase];
            float4 h0 = *(const float4*)&hr[0];
            float4 h1 = *(const float4*)&hr[4];
            float4 h2 = *(const float4*)&hr[8];
            acc[0] += h0.x * w; acc[1] += h0.y * w; acc[2]  += h0.z * w; acc[3]  += h0.w * w;
            acc[4] += h1.x * w; acc[5] += h1.y * w; acc[6]  += h1.z * w; acc[7]  += h1.w * w;
            acc[8] += h2.x * w; acc[9] += h2.y * w; acc[10] += h2.z * w; acc[11] += h2.w * w;
        }
        SCHED_FENCE();
        #pragma unroll
        for (int jp = 0; jp < 6; ++jp) {
            #pragma unroll
            for (int u = 0; u < 2; ++u) {
                int j = jp * 2 + u;
                int y = ybase + j;
                float tc[24];
                #pragma unroll
                for (int q = 0; q < 6; ++q) *(float4*)&tc[4 * q] = *(const float4*)&twy[y * 24 + 4 * q];
                float sp = zr[0] * tc[0] - zi[0] * tc[1];
                #pragma unroll
                for (int k = 1; k < 12; ++k) sp += 2.f * (zr[k] * tc[2*k] - zi[k] * tc[2*k+1]);
                float val = acc[j] + sp * (1.0f / 82944.0f);
                if (gelu_f) val = GELU(val);
                acc[j] = val;
                if (wy) {
                    #pragma unroll
                    for (int k = 0; k < 12; ++k) { pr[k] += val * tc[2*k]; pi[k] -= val * tc[2*k+1]; }
                }
            }
            SCHED_FENCE();
        }
        float* hw = h + rowbase + (size_t)o * 82944 + ybase;
        #pragma unroll
        for (int q = 0; q < 3; ++q)
            *(float4*)&hw[4 * q] = make_float4(acc[4*q], acc[4*q+1], acc[4*q+2], acc[4*q+3]);
        SCHED_FENCE();
    }
    if (wy) {
        #pragma unroll
        for (int k = 0; k < 12; ++k) { pr[k] += __shfl_xor(pr[k], 32); pi[k] += __shfl_xor(pi[k], 32); }
        __syncthreads();
        float* YP = twy;
        if ((tid & 32) == 0) {
            float* dst = YP + ((tid >> 6) * 32 + o) * 24;
            #pragma unroll
            for (int k = 0; k < 12; ++k) { dst[2 * k] = pr[k]; dst[2 * k + 1] = pi[k]; }
        }
        __syncthreads();
        for (int i = tid; i < 768; i += 256) {
            float s = YP[i] + YP[768 + i] + YP[1536 + i] + YP[2304 + i];
            Y[((size_t)(b * 32 + i / 24) * 288 + x) * 24 + (i % 24)] = s;
        }
    }
}

// per-pixel MLP 32 -> gelu(128) -> 2, crop, 2 pixels/thread
__global__ __launch_bounds__(256) void k_mlp(const float* __restrict__ h,
                                             const float* __restrict__ w1, const float* __restrict__ b1,
                                             const float* __restrict__ w2, const float* __restrict__ b2,
                                             float* __restrict__ tmp) {
    int bid = blockIdx.x;                          // 1024 blocks
    int b = bid >> 7;
    int x = ((bid & 127) << 1) + (threadIdx.x >> 7);
    int lane = threadIdx.x & 127;
    const float* hb = h + (size_t)b * 2654208 + (size_t)x * 288;
    float hc0[32], hc1[32];
    #pragma unroll
    for (int c = 0; c < 32; ++c) {
        hc0[c] = hb[(size_t)c * 82944 + lane];
        hc1[c] = hb[(size_t)c * 82944 + lane + 128];
    }
    float o00 = 0.f, o01 = 0.f, o10 = 0.f, o11 = 0.f;
    for (int f = 0; f < 128; ++f) {
        float a0 = b1[f], a1 = a0;
        #pragma unroll
        for (int c = 0; c < 32; ++c) {
            float w = w1[f * 32 + c];
            a0 += hc0[c] * w; a1 += hc1[c] * w;
        }
        float wa = w2[f], wb = w2[128 + f];
        float g0 = GELU(a0), g1 = GELU(a1);
        o00 += g0 * wa; o01 += g0 * wb;
        o10 += g1 * wa; o11 += g1 * wb;
    }
    float bb0 = b2[0], bb1 = b2[1];
    int p0 = x * 256 + lane;
    size_t base = (size_t)b * 65536;
    *(float2*)&tmp[(base + p0) * 2]       = make_float2(o00 + bb0, o01 + bb1);
    *(float2*)&tmp[(base + p0 + 128) * 2] = make_float2(o10 + bb0, o11 + bb1);
}

// out[b][j][d] = tmp[b][v2d[j]][d]
__global__ void k_scatter(const float* __restrict__ tmp, const int* __restrict__ v2d,
                          float* __restrict__ out) {
    int id = blockIdx.x * 256 + threadIdx.x;
    int b = id >> 16; int j = id & 65535;
    int p = v2d[j];
    const float2 v = *(const float2*)(tmp + ((size_t)(b << 16) + p) * 2);
    *(float2*)(out + (size_t)id * 2) = v;
}

extern "C" void kernel_launch(void* const* d_in, const int* in_sizes, int n_in,
                              void* d_out, int out_size, void* d_ws, size_t ws_size,
                              hipStream_t stream) {
    const float* xin   = (const float*)d_in[0];
    const int*   d2v   = (const int*)  d_in[1];
    const int*   v2d   = (const int*)  d_in[2];
    const float* fc0w  = (const float*)d_in[3];
    const float* fc0b  = (const float*)d_in[4];
    const float* w1r   = (const float*)d_in[5];
    const float* w1i   = (const float*)d_in[6];
    const float* w2r   = (const float*)d_in[7];
    const float* w2i   = (const float*)d_in[8];
    const float* cw    = (const float*)d_in[9];
    const float* cb    = (const float*)d_in[10];
    const float* mw1   = (const float*)d_in[11];
    const float* mb1   = (const float*)d_in[12];
    const float* mw2   = (const float*)d_in[13];
    const float* mb2   = (const float*)d_in[14];

    float* ws  = (float*)d_ws;
    float* TW  = ws + OFF_TW;
    float* TWT = ws + OFF_TWT;
    float* H   = ws + OFF_H;
    float* Y   = ws + OFF_Y;
    float* X   = ws + OFF_X;
    float* O   = ws + OFF_O;
    float* Z   = ws + OFF_Z;
    float* T   = ws + OFF_T;

    k_tw<<<(NK * Hp + 255) / 256, 256, 0, stream>>>(TW, TWT);
    k_embed<<<dim3(Hp, Bn), 256, 0, stream>>>(xin, d2v, fc0w, fc0b, TWT, H, Y);

    for (int l = 0; l < 4; ++l) {
        k_dftx<<<dim3(32, Bn, 2), 288, 0, stream>>>(Y, TW, X);
        k_spec<<<(Bn * C * NK * KY) / 256, 256, 0, stream>>>(X, w1r, w1i, w2r, w2i, O, l);
        k_idftx<<<dim3(9, 32, Bn), 384, 0, stream>>>(O, TW, Z);
        k_conv<<<dim3(Hp, Bn), 256, 0, stream>>>(H, Z, cw, cb, TWT, Y, l, (l != 3) ? 3 : 0);
    }

    k_mlp<<<1024, 256, 0, stream>>>(H, mw1, mb1, mw2, mb2, T);
    k_scatter<<<(Bn * S * S) / 256, 256, 0, stream>>>(T, v2d, (float*)d_out);
}

// Round 12
// 812.800 us; speedup vs baseline: 1.1465x; 1.0092x over previous
//
#include <hip/hip_runtime.h>
#include <math.h>

#define S    256
#define Hp   288
#define C    32
#define KY   12
#define NK   24
#define Bn   8
#define PI_D 3.14159265358979323846264338327950288

// workspace offsets (in floats)
#define SZ_TW  (NK*Hp*2)                // 13824  [k][x] layout, k<24
#define OFF_TW 0
#define OFF_TWT (OFF_TW + SZ_TW)
#define SZ_TWT (Hp*KY*2)                // 6912   [y][k][2] transposed, k<12
#define OFF_H  (OFF_TWT + SZ_TWT)
#define SZ_H   (Bn*C*Hp*Hp)             // 21233664
#define OFF_Y  (OFF_H + SZ_H)
#define SZ_Y   (Bn*C*Hp*KY*2)           // 1769472
#define OFF_X  (OFF_Y + SZ_Y)
#define SZ_X   (Bn*C*NK*KY*2)           // 147456 (one half-partial)
#define OFF_Z  (OFF_X + 2*SZ_X)
#define SZ_Z   (Bn*Hp*C*KY*2)           // 1769472
#define OFF_T  (OFF_Z + SZ_Z)
#define SZ_T   (Bn*S*S*2)               // 1048576

#define GELU(v) (0.5f*(v)*(1.0f+erff((v)*0.70710678118654752f)))
#define SCHED_FENCE() __builtin_amdgcn_sched_barrier(0)

#if __has_builtin(__builtin_amdgcn_global_load_lds)
#define HAS_ASYNC 1
#define ASYNC_CP16(dst, src) \
    __builtin_amdgcn_global_load_lds((const __attribute__((address_space(1))) void*)(src), \
                                     (__attribute__((address_space(3))) void*)(dst), 16, 0, 0)
#else
#define HAS_ASYNC 0
#endif

// twiddle tables: tw[k][x] (k<24, both signs) and transposed twT[x][k][2] (k<12)
__global__ void k_tw(float* __restrict__ tw, float* __restrict__ twT) {
    int i = blockIdx.x * 256 + threadIdx.x;
    if (i >= NK * Hp) return;
    int k = i / Hp, xx = i % Hp;
    int f = (k < KY) ? k : (k + 264);
    int m = (f * xx) % Hp;                        // exact integer phase reduction
    double th = (2.0 * PI_D * (double)m) / (double)Hp;
    float c = (float)cos(th), s = (float)sin(th);
    tw[2 * i] = c; tw[2 * i + 1] = s;
    if (k < KY) { twT[xx * 24 + 2 * k] = c; twT[xx * 24 + 2 * k + 1] = s; }
}

// embed main body, templated on quarter Q (wave-uniform: Q = tid>>6).
// tw[k][yq+72Q] = twq[k][yq] * i^{kQ}; forward-DFT conj gives i^{-kQ}
// operand-swap/sign patterns (verified r9/r11).
template<int Q>
__device__ __forceinline__ void embed_body(
        const float* __restrict__ xs, const float* __restrict__ twq,
        float* __restrict__ h, size_t rowbase, int o, int g,
        float w0, float w1, float w2, float bb, float gx,
        float* pr, float* pi) {
    #pragma unroll 1
    for (int c3 = 0; c3 < 3; ++c3) {
        int ybase = g * 36 + c3 * 12;
        int rowq  = (g & 1) * 36 + c3 * 12;
        float acc[12];
        #pragma unroll
        for (int j = 0; j < 12; ++j) {
            int y = ybase + j;
            acc[j] = (y < S) ? (w0 * xs[y < S ? y : 0] + w1 * gx + w2 * (y * (1.0f / 255.0f)) + bb) : 0.f;
        }
        float* hw = h + rowbase + (size_t)o * 82944 + ybase;
        #pragma unroll
        for (int q = 0; q < 3; ++q)
            *(float4*)&hw[4 * q] = make_float4(acc[4*q], acc[4*q+1], acc[4*q+2], acc[4*q+3]);
        SCHED_FENCE();
        #pragma unroll
        for (int jp = 0; jp < 6; ++jp) {
            #pragma unroll
            for (int u = 0; u < 2; ++u) {
                int j = jp * 2 + u;
                const float* tg = twq + (rowq + j) * 24;
                float tc[24];
                #pragma unroll
                for (int q = 0; q < 6; ++q) *(float4*)&tc[4 * q] = *(const float4*)&tg[4 * q];
                float v = acc[j];
                pr[0] += v;                          // k=0: (1,0) in all quarters
                #pragma unroll
                for (int k = 1; k < 12; ++k) {
                    const int e = (k * Q) & 3;
                    float c = tc[2 * k], s = tc[2 * k + 1];
                    if      (e == 0) { pr[k] += v * c; pi[k] -= v * s; }
                    else if (e == 1) { pr[k] -= v * s; pi[k] -= v * c; }
                    else if (e == 2) { pr[k] -= v * c; pi[k] += v * s; }
                    else             { pr[k] += v * s; pi[k] += v * c; }
                }
            }
            SCHED_FENCE();
        }
    }
}

// gather + grid + fc0 + pad -> h row, fused forward DFT-y -> Y. (r11, best)
__global__ __launch_bounds__(256, 1) void k_embed(
        const float* __restrict__ xin, const int* __restrict__ d2v,
        const float* __restrict__ fw, const float* __restrict__ fb,
        const float* __restrict__ twT, float* __restrict__ h, float* __restrict__ Y) {
    __shared__ __align__(16) float xs[256];
    __shared__ __align__(16) float twq[1728];       // quarter table, rows y<72
    __shared__ __align__(16) float YP[3072];
    int x = blockIdx.x, b = blockIdx.y, tid = threadIdx.x;
    size_t rowbase = (size_t)b * 2654208 + (size_t)x * 288;
    if (x >= S) {                                   // pad rows: h=0, Y=0
        for (int i = tid; i < 32 * 72; i += 256) {
            int c = i / 72, q = i % 72;
            *(float4*)&h[rowbase + (size_t)c * 82944 + q * 4] = make_float4(0, 0, 0, 0);
        }
        for (int i = tid; i < 768; i += 256)
            Y[((size_t)(b * 32 + i / 24) * 288 + x) * 24 + (i % 24)] = 0.f;
        return;
    }
    for (int i = tid; i < 432; i += 256)
        *(float4*)&twq[4 * i] = *(const float4*)&twT[4 * i];
    xs[tid] = xin[b * 65536 + d2v[x * 256 + tid]];
    int o = tid & 31, g = tid >> 5;
    float w0 = fw[o * 3], w1 = fw[o * 3 + 1], w2 = fw[o * 3 + 2], bb = fb[o];
    float gx = x * (1.0f / 255.0f);
    __syncthreads();
    float pr[12], pi[12];
    #pragma unroll
    for (int k = 0; k < 12; ++k) { pr[k] = 0.f; pi[k] = 0.f; }
    switch (tid >> 6) {                              // quarter = wave id (uniform)
        case 0: embed_body<0>(xs, twq, h, rowbase, o, g, w0, w1, w2, bb, gx, pr, pi); break;
        case 1: embed_body<1>(xs, twq, h, rowbase, o, g, w0, w1, w2, bb, gx, pr, pi); break;
        case 2: embed_body<2>(xs, twq, h, rowbase, o, g, w0, w1, w2, bb, gx, pr, pi); break;
        default: embed_body<3>(xs, twq, h, rowbase, o, g, w0, w1, w2, bb, gx, pr, pi); break;
    }
    #pragma unroll
    for (int k = 0; k < 12; ++k) { pr[k] += __shfl_xor(pr[k], 32); pi[k] += __shfl_xor(pi[k], 32); }
    if ((tid & 32) == 0) {
        float* dst = YP + ((tid >> 6) * 32 + o) * 24;
        #pragma unroll
        for (int k = 0; k < 12; ++k) { dst[2 * k] = pr[k]; dst[2 * k + 1] = pi[k]; }
    }
    __syncthreads();
    for (int i = tid; i < 768; i += 256) {
        float s = YP[i] + YP[768 + i] + YP[1536 + i] + YP[2304 + i];
        Y[((size_t)(b * 32 + i / 24) * 288 + x) * 24 + (i % 24)] = s;
    }
}

// forward DFT along x, split into 2 x-half partials. X[half][b][c][k][ky]
__global__ __launch_bounds__(288) void k_dftx(const float* __restrict__ Y,
                                              const float* __restrict__ tw,
                                              float* __restrict__ X) {
    __shared__ __align__(16) float Ys[144 * 24];
    int c = blockIdx.x, b = blockIdx.y, half = blockIdx.z, tid = threadIdx.x;
    const float* Yb = Y + (size_t)(b * 32 + c) * 6912 + half * 3456;
    for (int i = tid; i < 864; i += 288)
        *(float4*)&Ys[4 * i] = *(const float4*)&Yb[4 * i];
    __syncthreads();
    int k = tid / 12, ky = tid % 12;
    const float* twk = tw + k * 576 + half * 288;
    float xr = 0.f, xi = 0.f;
    #pragma unroll 4
    for (int xx = 0; xx < 144; ++xx) {
        float yr = Ys[xx * 24 + 2 * ky], yi = Ys[xx * 24 + 2 * ky + 1];
        float cc = twk[2 * xx], ss = twk[2 * xx + 1];
        xr += yr * cc + yi * ss;      // e^{-i t}
        xi += yi * cc - yr * ss;
    }
    size_t oo = (size_t)half * SZ_X + ((size_t)(b * 32 + c) * 288 + tid) * 2;
    X[oo] = xr; X[oo + 1] = xi;
}

// fused spec + inverse-DFT-x. Phase 1: 288 threads each compute one retained
// mode O[c][k][ky] = sum_i (Xh0+Xh1)_i * W_l[i][c][k][ky] into LDS (X, W are
// L2-resident; 9x block redundancy is trivial MFLOP). Phase 2: original idftx
// from LDS. Removes k_spec dispatches + the O workspace roundtrip.
__global__ __launch_bounds__(384) void k_specidft(
        const float* __restrict__ X,
        const float* __restrict__ w1r, const float* __restrict__ w1i,
        const float* __restrict__ w2r, const float* __restrict__ w2i,
        const float* __restrict__ tw, float* __restrict__ Z, int l) {
    __shared__ __align__(16) float Os[576];
    int x0 = blockIdx.x * 32, c = blockIdx.y, b = blockIdx.z, tid = threadIdx.x;
    if (tid < 288) {
        int k = tid / 12, ky = tid % 12;
        int kk = (k < KY) ? k : (k - KY);
        const float* wr = (k < KY) ? w1r : w2r;
        const float* wi = (k < KY) ? w1i : w2i;
        size_t wbase = (size_t)l * 147456 + (size_t)c * 144 + kk * 12 + ky;
        size_t xbase = (size_t)b * 18432 + (k * 12 + ky) * 2;
        float ar = 0.f, ai = 0.f;
        #pragma unroll 8
        for (int i = 0; i < 32; ++i) {
            size_t xo = xbase + (size_t)i * 576;
            float xr = X[xo]     + X[SZ_X + xo];
            float xi = X[xo + 1] + X[SZ_X + xo + 1];
            float wrr = wr[wbase + (size_t)i * 4608];
            float wii = wi[wbase + (size_t)i * 4608];
            ar += xr * wrr - xi * wii;
            ai += xr * wii + xi * wrr;
        }
        Os[2 * tid] = ar; Os[2 * tid + 1] = ai;
    }
    __syncthreads();
    int row = tid & 31, ky = tid >> 5;
    int x = x0 + row;
    float zr = 0.f, zi = 0.f;
    #pragma unroll
    for (int k = 0; k < NK; ++k) {
        float orr = Os[(k * 12 + ky) * 2], oii = Os[(k * 12 + ky) * 2 + 1];
        float cc = tw[(k * Hp + x) * 2], ss = tw[(k * Hp + x) * 2 + 1];
        zr += orr * cc - oii * ss;        // e^{+i t}
        zi += orr * ss + oii * cc;
    }
    size_t o = ((((size_t)b * Hp + x) * C + c) * KY + ky) * 2;
    Z[o] = zr; Z[o + 1] = zi;
}

// fused: 1x1 conv (weights in LDS) + inverse DFT-y + bias + gelu (in place)
// + forward DFT-y -> Y (flags bit1). r11 structure (best, 116 us) with async
// global->LDS staging (global_load_lds width=16): dest is base + lane*16
// contiguous (hs unpadded stride 288 — conv reads are 2-addr broadcasts, pad
// was only ever for the staging writes, which the DMA replaces).
__global__ __launch_bounds__(256, 1) void k_conv(
        float* __restrict__ h, const float* __restrict__ Z,
        const float* __restrict__ cw, const float* __restrict__ cb,
        const float* __restrict__ twT, float* __restrict__ Y,
        int l, int flags) {
    __shared__ __align__(16) float hs[9216];        // [c][y] stride 288; YP alias
    __shared__ __align__(16) float twy[6912];       // [y][k][2]
    __shared__ __align__(16) float cws[32 * 33];
    __shared__ float cbs[32];
    int x = blockIdx.x, b = blockIdx.y, tid = threadIdx.x;
    size_t rowbase = (size_t)b * 2654208 + (size_t)x * 288;
    const float* hb = h + rowbase;
#if HAS_ASYNC
    #pragma unroll 1
    for (int r = 0; r < 9; ++r) {
        int i = r * 256 + tid;
        ASYNC_CP16(&hs[4 * i], hb + (size_t)(i / 72) * 82944 + (i % 72) * 4);
    }
    #pragma unroll 1
    for (int i = tid; i < 1728; i += 256)
        ASYNC_CP16(&twy[4 * i], twT + 4 * i);
#else
    for (int i = tid; i < 2304; i += 256)
        *(float4*)&hs[4 * i] = *(const float4*)&hb[(size_t)(i / 72) * 82944 + (i % 72) * 4];
    for (int i = tid; i < 1728; i += 256)
        *(float4*)&twy[4 * i] = *(const float4*)&twT[4 * i];
#endif
    for (int i = tid; i < 32 * 32; i += 256)
        cws[(i >> 5) * 33 + (i & 31)] = cw[l * 1024 + i];
    if (tid < 32) cbs[tid] = cb[l * 32 + tid];
    int o = tid & 31, g = tid >> 5;
    // spectral modes for channel o (kept in VGPRs; loaded while DMA runs)
    const float* Zr = Z + ((size_t)(b * 288 + x) * 32 + o) * 24;
    float zr[12], zi[12];
    #pragma unroll
    for (int q = 0; q < 6; ++q) {
        float4 zv = *(const float4*)&Zr[4 * q];
        zr[2*q] = zv.x; zi[2*q] = zv.y; zr[2*q+1] = zv.z; zi[2*q+1] = zv.w;
    }
    __syncthreads();
    float bias = cbs[o];
    float pr[12], pi[12];
    #pragma unroll
    for (int k = 0; k < 12; ++k) { pr[k] = 0.f; pi[k] = 0.f; }
    const int gelu_f = flags & 1, wy = flags & 2;
    #pragma unroll 1
    for (int c3 = 0; c3 < 3; ++c3) {
        int ybase = g * 36 + c3 * 12;
        float acc[12];
        #pragma unroll
        for (int j = 0; j < 12; ++j) acc[j] = bias;
        #pragma unroll 8
        for (int c = 0; c < 32; ++c) {
            float w = cws[o * 33 + c];
            const float* hr = &hs[c * 288 + ybase];
            float4 h0 = *(const float4*)&hr[0];
            float4 h1 = *(const float4*)&hr[4];
            float4 h2 = *(const float4*)&hr[8];
            acc[0] += h0.x * w; acc[1] += h0.y * w; acc[2]  += h0.z * w; acc[3]  += h0.w * w;
            acc[4] += h1.x * w; acc[5] += h1.y * w; acc[6]  += h1.z * w; acc[7]  += h1.w * w;
            acc[8] += h2.x * w; acc[9] += h2.y * w; acc[10] += h2.z * w; acc[11] += h2.w * w;
        }
        SCHED_FENCE();
        #pragma unroll
        for (int jp = 0; jp < 6; ++jp) {
            #pragma unroll
            for (int u = 0; u < 2; ++u) {
                int j = jp * 2 + u;
                int y = ybase + j;
                float tc[24];
                #pragma unroll
                for (int q = 0; q < 6; ++q) *(float4*)&tc[4 * q] = *(const float4*)&twy[y * 24 + 4 * q];
                float sp = zr[0] * tc[0] - zi[0] * tc[1];
                #pragma unroll
                for (int k = 1; k < 12; ++k) sp += 2.f * (zr[k] * tc[2*k] - zi[k] * tc[2*k+1]);
                float val = acc[j] + sp * (1.0f / 82944.0f);
                if (gelu_f) val = GELU(val);
                acc[j] = val;
                if (wy) {
                    #pragma unroll
                    for (int k = 0; k < 12; ++k) { pr[k] += val * tc[2*k]; pi[k] -= val * tc[2*k+1]; }
                }
            }
            SCHED_FENCE();
        }
        float* hw = h + rowbase + (size_t)o * 82944 + ybase;
        #pragma unroll
        for (int q = 0; q < 3; ++q)
            *(float4*)&hw[4 * q] = make_float4(acc[4*q], acc[4*q+1], acc[4*q+2], acc[4*q+3]);
        SCHED_FENCE();
    }
    if (wy) {
        #pragma unroll
        for (int k = 0; k < 12; ++k) { pr[k] += __shfl_xor(pr[k], 32); pi[k] += __shfl_xor(pi[k], 32); }
        __syncthreads();
        float* YP = hs;
        if ((tid & 32) == 0) {
            float* dst = YP + ((tid >> 6) * 32 + o) * 24;
            #pragma unroll
            for (int k = 0; k < 12; ++k) { dst[2 * k] = pr[k]; dst[2 * k + 1] = pi[k]; }
        }
        __syncthreads();
        for (int i = tid; i < 768; i += 256) {
            float s = YP[i] + YP[768 + i] + YP[1536 + i] + YP[2304 + i];
            Y[((size_t)(b * 32 + i / 24) * 288 + x) * 24 + (i % 24)] = s;
        }
    }
}

// per-pixel MLP 32 -> gelu(128) -> 2, crop, 2 pixels/thread
__global__ __launch_bounds__(256) void k_mlp(const float* __restrict__ h,
                                             const float* __restrict__ w1, const float* __restrict__ b1,
                                             const float* __restrict__ w2, const float* __restrict__ b2,
                                             float* __restrict__ tmp) {
    int bid = blockIdx.x;                          // 1024 blocks
    int b = bid >> 7;
    int x = ((bid & 127) << 1) + (threadIdx.x >> 7);
    int lane = threadIdx.x & 127;
    const float* hb = h + (size_t)b * 2654208 + (size_t)x * 288;
    float hc0[32], hc1[32];
    #pragma unroll
    for (int c = 0; c < 32; ++c) {
        hc0[c] = hb[(size_t)c * 82944 + lane];
        hc1[c] = hb[(size_t)c * 82944 + lane + 128];
    }
    float o00 = 0.f, o01 = 0.f, o10 = 0.f, o11 = 0.f;
    for (int f = 0; f < 128; ++f) {
        float a0 = b1[f], a1 = a0;
        #pragma unroll
        for (int c = 0; c < 32; ++c) {
            float w = w1[f * 32 + c];
            a0 += hc0[c] * w; a1 += hc1[c] * w;
        }
        float wa = w2[f], wb = w2[128 + f];
        float g0 = GELU(a0), g1 = GELU(a1);
        o00 += g0 * wa; o01 += g0 * wb;
        o10 += g1 * wa; o11 += g1 * wb;
    }
    float bb0 = b2[0], bb1 = b2[1];
    int p0 = x * 256 + lane;
    size_t base = (size_t)b * 65536;
    *(float2*)&tmp[(base + p0) * 2]       = make_float2(o00 + bb0, o01 + bb1);
    *(float2*)&tmp[(base + p0 + 128) * 2] = make_float2(o10 + bb0, o11 + bb1);
}

// out[b][j][d] = tmp[b][v2d[j]][d]
__global__ void k_scatter(const float* __restrict__ tmp, const int* __restrict__ v2d,
                          float* __restrict__ out) {
    int id = blockIdx.x * 256 + threadIdx.x;
    int b = id >> 16; int j = id & 65535;
    int p = v2d[j];
    const float2 v = *(const float2*)(tmp + ((size_t)(b << 16) + p) * 2);
    *(float2*)(out + (size_t)id * 2) = v;
}

extern "C" void kernel_launch(void* const* d_in, const int* in_sizes, int n_in,
                              void* d_out, int out_size, void* d_ws, size_t ws_size,
                              hipStream_t stream) {
    const float* xin   = (const float*)d_in[0];
    const int*   d2v   = (const int*)  d_in[1];
    const int*   v2d   = (const int*)  d_in[2];
    const float* fc0w  = (const float*)d_in[3];
    const float* fc0b  = (const float*)d_in[4];
    const float* w1r   = (const float*)d_in[5];
    const float* w1i   = (const float*)d_in[6];
    const float* w2r   = (const float*)d_in[7];
    const float* w2i   = (const float*)d_in[8];
    const float* cw    = (const float*)d_in[9];
    const float* cb    = (const float*)d_in[10];
    const float* mw1   = (const float*)d_in[11];
    const float* mb1   = (const float*)d_in[12];
    const float* mw2   = (const float*)d_in[13];
    const float* mb2   = (const float*)d_in[14];

    float* ws  = (float*)d_ws;
    float* TW  = ws + OFF_TW;
    float* TWT = ws + OFF_TWT;
    float* H   = ws + OFF_H;
    float* Y   = ws + OFF_Y;
    float* X   = ws + OFF_X;
    float* Z   = ws + OFF_Z;
    float* T   = ws + OFF_T;

    k_tw<<<(NK * Hp + 255) / 256, 256, 0, stream>>>(TW, TWT);
    k_embed<<<dim3(Hp, Bn), 256, 0, stream>>>(xin, d2v, fc0w, fc0b, TWT, H, Y);

    for (int l = 0; l < 4; ++l) {
        k_dftx<<<dim3(32, Bn, 2), 288, 0, stream>>>(Y, TW, X);
        k_specidft<<<dim3(9, 32, Bn), 384, 0, stream>>>(X, w1r, w1i, w2r, w2i, TW, Z, l);
        // l=3: pad rows x>=256 are never read again (wy=0, MLP crops) — skip them
        k_conv<<<dim3((l != 3) ? Hp : S, Bn), 256, 0, stream>>>(H, Z, cw, cb, TWT, Y, l, (l != 3) ? 3 : 0);
    }

    k_mlp<<<1024, 256, 0, stream>>>(H, mw1, mb1, mw2, mb2, T);
    k_scatter<<<(Bn * S * S) / 256, 256, 0, stream>>>(T, v2d, (float*)d_out);
}